// Round 10
// baseline (262.193 us; speedup 1.0000x reference)
//
#include <hip/hip_runtime.h>

#define BB 64
#define CC 128
#define TT 4096
#define NN 6            // KNOT + 2
#define HH 819.0f       // (T-1)/(KNOT+1) = 4095/5, exact in fp32
#define NROW (BB * CC)
#define NSPAN 5
#define TABBYTES ((size_t)NROW * NSPAN * 16)
#define PADSZ (TT + TT / 32)    // 4224 floats = 16.9 KB
#define CHN 4                   // chunks per row
#define CEPT 16                 // elements per lane per chunk (4*16*64 = 4096)

typedef float f4 __attribute__((ext_vector_type(4)));

__device__ __forceinline__ void nt_store4(float* p, f4 v) {
    __builtin_nontemporal_store(v, (f4*)p);
}

// LDS pad: +1 float per 32 breaks power-of-2 stride conflicts.
__device__ __forceinline__ int padi(int j) { return j + (j >> 5); }

// ---- 6x6 not-a-knot solve; A compile-time constant -> multipliers fold ----
__device__ __forceinline__ void spline_solve(const float* __restrict__ yy,
                                             int b, int c, float* y, float* Mv)
{
    #pragma unroll
    for (int k = 0; k < NN; ++k)
        y[k] = yy[((size_t)b * NN + k) * CC + c];
    float Aug[NN][NN + 1];
    #pragma unroll
    for (int i = 0; i < NN; ++i)
        #pragma unroll
        for (int j = 0; j < NN + 1; ++j)
            Aug[i][j] = 0.0f;
    Aug[0][0] = 1.0f;  Aug[0][1] = -2.0f;  Aug[0][2] = 1.0f;
    Aug[5][3] = 1.0f;  Aug[5][4] = -2.0f;  Aug[5][5] = 1.0f;
    #pragma unroll
    for (int i = 1; i < NN - 1; ++i) {
        Aug[i][i - 1] = HH / 6.0f;
        Aug[i][i]     = 2.0f * HH / 3.0f;
        Aug[i][i + 1] = HH / 6.0f;
        Aug[i][NN]    = (y[i + 1] - 2.0f * y[i] + y[i - 1]) / HH;
    }
    #pragma unroll
    for (int k = 0; k < NN; ++k) {
        float inv = 1.0f / Aug[k][k];
        #pragma unroll
        for (int i = k + 1; i < NN; ++i) {
            float m = Aug[i][k] * inv;
            #pragma unroll
            for (int j = k; j < NN + 1; ++j)
                Aug[i][j] -= m * Aug[k][j];
        }
    }
    #pragma unroll
    for (int i = NN - 1; i >= 0; --i) {
        float s = Aug[i][NN];
        #pragma unroll
        for (int j = i + 1; j < NN; ++j)
            s -= Aug[i][j] * Mv[j];
        Mv[i] = s / Aug[i][i];
    }
}

__device__ __forceinline__ void horner_coefs(const float* y, const float* Mv,
                                             f4* out5)
{
    const float invh  = 1.0f / HH;
    const float inv6h = 1.0f / (6.0f * HH);
    #pragma unroll
    for (int s = 0; s < NSPAN; ++s) {
        f4 cf;
        cf.x = y[s];
        cf.y = (y[s + 1] - y[s]) * invh - Mv[s] * (HH / 3.0f) - Mv[s + 1] * (HH / 6.0f);
        cf.z = Mv[s] * 0.5f;
        cf.w = (Mv[s + 1] - Mv[s]) * inv6h;
        out5[s] = cf;
    }
}

// ---- setup: per-(row, span) Horner coeffs (a,b,c,d) into workspace ----
__global__ __launch_bounds__(256) void spline_coef_kernel(
    const float* __restrict__ yy, f4* __restrict__ tab)
{
    const int row = blockIdx.x * 256 + threadIdx.x;   // 8192 rows, coalesced in c
    const int b = row / CC;
    const int c = row % CC;
    float y[NN], Mv[NN];
    spline_solve(yy, b, c, y, Mv);
    f4 cf[NSPAN];
    horner_coefs(y, Mv, cf);
    #pragma unroll
    for (int s = 0; s < NSPAN; ++s)
        tab[row * NSPAN + s] = cf[s];
}

// ============================ main kernel ==================================
// ONE WAVE = ONE ROW. Zero __syncthreads. 64 lanes x 64 elements, two-pass:
//   A) per-lane chunk subtotals -> wave scans -> offsets + scale (shfl only)
//   B) recompute curve, form xp, scatter final values to LDS
// then one lgkmcnt drain and coalesced NT restage. All inter-lane data moves
// by shfl; LDS hazards are wave-internal.
template <int TABLE>
__global__ __launch_bounds__(64) void timewarp_kernel(
    const float* __restrict__ x,
    const float* __restrict__ yy,
    const float* __restrict__ mask_rand,
    const f4* __restrict__ tab,
    float* __restrict__ out)
{
    const int row  = blockIdx.x;         // b*C + c
    const int b    = row / CC;
    const int lane = threadIdx.x;        // 0..63

    const float* xrow = x + (size_t)row * TT;
    float* orow       = out + (size_t)row * TT;

    // mask_rand >= 0.5 -> bit-exact copy (uniform per block)
    if (!(mask_rand[b] < 0.5f)) {
        const f4* xi = (const f4*)xrow;
        #pragma unroll
        for (int k = 0; k < 16; ++k)
            nt_store4(orow + 4 * (lane + 64 * k), xi[lane + 64 * k]);
        return;
    }

    __shared__ float sres[PADSZ];        // padded scatter target (one wave's row)

    // ---- span geometry per chunk (lane owns t in [c*1024+lane*16, +16)) ----
    int   idxA[CHN], idxB[CHN];
    float xlA[CHN], xlB[CHN], tbb[CHN];
    #pragma unroll
    for (int c = 0; c < CHN; ++c) {
        int t0c = c * 1024 + lane * CEPT;
        int ia = t0c / 819;  if (ia > 4) ia = 4;
        int ib = ia + 1;     if (ib > 4) ib = 4;
        idxA[c] = ia;  idxB[c] = ib;
        xlA[c] = (float)ia * HH;
        xlB[c] = (float)ib * HH;
        tbb[c] = (float)((ia + 1) * 819);
    }

    // ---- all global loads issued up front (latency hidden under pass A) ----
    f4 fv[CHN * 4];                       // this lane's 64 x values
    #pragma unroll
    for (int c = 0; c < CHN; ++c)
        #pragma unroll
        for (int q = 0; q < 4; ++q)
            fv[c * 4 + q] = *(const f4*)(xrow + c * 1024 + lane * CEPT + 4 * q);

    f4 cfA[CHN], cfB[CHN];
    if (TABLE) {
        #pragma unroll
        for (int c = 0; c < CHN; ++c) {
            cfA[c] = tab[row * NSPAN + idxA[c]];   // L1/L2-hot: 80 B per row
            cfB[c] = tab[row * NSPAN + idxB[c]];
        }
    } else {
        float y[NN], Mv[NN];
        f4 cf[NSPAN];
        spline_solve(yy, b, row % CC, y, Mv);
        horner_coefs(y, Mv, cf);
        #pragma unroll
        for (int c = 0; c < CHN; ++c) {
            f4 a = cf[0], bb = cf[0];
            #pragma unroll
            for (int s = 1; s < NSPAN; ++s) {      // static indices -> cndmask
                if (idxA[c] >= s) a  = cf[s];
                if (idxB[c] >= s) bb = cf[s];
            }
            cfA[c] = a;  cfB[c] = bb;
        }
    }

    // ---- pass A: per-chunk per-lane curve subtotal (sequential order) ----
    float ct[CHN];
    #pragma unroll
    for (int c = 0; c < CHN; ++c) {
        float t0f = (float)(c * 1024 + lane * CEPT);
        float acc = 0.0f;
        #pragma unroll
        for (int k = 0; k < CEPT; ++k) {
            float ft = t0f + (float)k;
            bool inB = ft >= tbb[c];
            f4    cf = inB ? cfB[c] : cfA[c];
            float s  = ft - (inB ? xlB[c] : xlA[c]);
            acc += fmaf(s, fmaf(s, fmaf(s, cf.w, cf.z), cf.y), cf.x);
        }
        ct[c] = acc;
    }

    // ---- wave scans per chunk (shfl; no LDS, no barrier) ----
    float incl[CHN], excl[CHN], ctT[CHN];
    #pragma unroll
    for (int c = 0; c < CHN; ++c) {
        float v = ct[c];
        #pragma unroll
        for (int d = 1; d < 64; d <<= 1) {
            float u = __shfl_up(v, d, 64);
            if (lane >= d) v += u;
        }
        incl[c] = v;
        excl[c] = __shfl_up(v, 1, 64);   // lane 0: unused (selects cp[c])
        ctT[c]  = __shfl(v, 63, 64);     // chunk total, scan-order bits
    }
    float cp[CHN + 1];
    cp[0] = 0.0f;
    #pragma unroll
    for (int c = 0; c < CHN; ++c)
        cp[c + 1] = cp[c] + ctT[c];      // same add order in every lane
    const float scale = 4095.0f / cp[CHN];

    // ---- pass B per chunk: xp + direct scatter of final values ----
    #pragma unroll
    for (int c = 0; c < CHN; ++c) {
        const int   t0i = c * 1024 + lane * CEPT;
        const float t0f = (float)t0i;
        // exclusive offset; lane 0 takes cp[c] directly (avoids +0.0f bit hazard)
        float run = (lane == 0) ? cp[c] : (cp[c] + excl[c]);
        float xp[CEPT + 1];
        #pragma unroll
        for (int k = 0; k < CEPT; ++k) {
            float ft = t0f + (float)k;
            bool inB = ft >= tbb[c];
            f4    cf = inB ? cfB[c] : cfA[c];
            float s  = ft - (inB ? xlB[c] : xlA[c]);
            run += fmaf(s, fmaf(s, fmaf(s, cf.w, cf.z), cf.y), cf.x);
            xp[k] = run * scale;
        }
        // boundary xp[16]: ((cp[c] + incl[c]) + curve(t0+16)) * scale is
        // bit-identical to the neighbor's (off + first-curve) * scale:
        //  - lanes 0..62: neighbor's off = cp[c] + excl = cp[c] + incl(bits)
        //  - lane 63:     next chunk lane-0 off = cp[c+1] = cp[c] + ctT[c]
        //                 = cp[c] + incl[c] (same operands, same op)
        // and the coefficient set selected for ft = t0+16 equals the
        // neighbor's first-element selection (span-boundary case analysis).
        {
            float ft = t0f + (float)CEPT;
            bool inB = ft >= tbb[c];
            f4    cf = inB ? cfB[c] : cfA[c];
            float s  = ft - (inB ? xlB[c] : xlA[c]);
            float cN = fmaf(s, fmaf(s, fmaf(s, cf.w, cf.z), cf.y), cf.x);
            xp[CEPT] = ((cp[c] + incl[c]) + cN) * scale;
        }

        // this lane's 16 fp values + the boundary fp (neighbor's first)
        float fpl[CEPT];
        #pragma unroll
        for (int q = 0; q < 4; ++q) {
            f4 v = fv[c * 4 + q];
            fpl[4 * q + 0] = v.x; fpl[4 * q + 1] = v.y;
            fpl[4 * q + 2] = v.z; fpl[4 * q + 3] = v.w;
        }
        float fb;
        {
            float nxt_same  = __shfl_down(fv[c * 4].x, 1, 64);        // lane+1 first
            float nxt_chunk = __shfl(fv[((c + 1) & 3) * 4].x, 0, 64); // next chunk lane 0
            fb = (lane == 63) ? nxt_chunk : nxt_same;   // c=3,lane63: unused
        }

        // scatter: segment j owns q in [ceil(xp[j]), ceil(xp[j+1]))
        #pragma unroll
        for (int k = 0; k < CEPT; ++k) {
            const int seg = t0i + k;
            if (seg < TT - 1) {
                float xa = xp[k], xb = xp[k + 1];
                float fa = fpl[k];
                float fbk = (k < CEPT - 1) ? fpl[k + 1] : fb;
                float d  = xb - xa;
                float slope = (d > 0.0f) ? (fbk - fa) * __builtin_amdgcn_rcpf(d) : 0.0f;
                float a0 = fmaf(-xa, slope, fa);
                int qlo = (int)ceilf(xa);  if (qlo < 0) qlo = 0;
                int qhi = (int)ceilf(xb);  if (qhi > TT) qhi = TT;
                for (int q = qlo; q < qhi; ++q)
                    sres[padi(q)] = fmaf((float)q, slope, a0);
            }
        }
        if (c == 0 && lane == 0) {              // head: q < xp[0] -> fp[0]
            int q1 = (int)ceilf(xp[0]);  if (q1 > TT) q1 = TT;
            for (int q = 0; q < q1; ++q) sres[padi(q)] = fpl[0];
        }
        if (c == CHN - 1 && lane == 63) {       // tail: q >= xp[4095] -> fp[4095]
            int q0 = (int)ceilf(xp[CEPT - 1]);  if (q0 < 0) q0 = 0;
            for (int q = q0; q < TT; ++q) sres[padi(q)] = fpl[CEPT - 1];
        }
    }

    // ---- drain LDS writes (wave-internal), then coalesced NT restage ----
    asm volatile("s_waitcnt lgkmcnt(0)" ::: "memory");
    #pragma unroll
    for (int k = 0; k < 16; ++k) {
        int i4  = lane + 64 * k;
        int fb4 = 4 * i4;
        int p   = padi(fb4);
        f4 v;
        v.x = sres[p + 0];
        v.y = sres[p + 1];
        v.z = sres[p + 2];
        v.w = sres[p + 3];
        nt_store4(orow + fb4, v);
    }
}

extern "C" void kernel_launch(void* const* d_in, const int* in_sizes, int n_in,
                              void* d_out, int out_size, void* d_ws, size_t ws_size,
                              hipStream_t stream) {
    const float* x    = (const float*)d_in[0];   // (64,128,4096) fp32
    const float* yy   = (const float*)d_in[1];   // (64,6,128)    fp32
    const float* mask = (const float*)d_in[2];   // (64,1,1)      fp32
    float* out = (float*)d_out;                  // (64,128,4096) fp32

    if (d_ws != nullptr && ws_size >= TABBYTES) {
        f4* tab = (f4*)d_ws;
        spline_coef_kernel<<<dim3(NROW / 256), dim3(256), 0, stream>>>(yy, tab);
        timewarp_kernel<1><<<dim3(NROW), dim3(64), 0, stream>>>(x, yy, mask, tab, out);
    } else {
        timewarp_kernel<0><<<dim3(NROW), dim3(64), 0, stream>>>(x, yy, mask, nullptr, out);
    }
}

// Round 11
// 248.298 us; speedup vs baseline: 1.0560x; 1.0560x over previous
//
#include <hip/hip_runtime.h>

#define BB 64
#define CC 128
#define TT 4096
#define NN 6            // KNOT + 2
#define HH 819.0f       // (T-1)/(KNOT+1) = 4095/5, exact in fp32
#define NTHR 512
#define EPT 8           // curve elements per thread (NTHR*EPT == TT)
#define NWAVE (NTHR / 64)
#define NROW (BB * CC)
#define NSPAN 5
#define TABBYTES ((size_t)NROW * NSPAN * 16)
#define PADSZ (TT + TT / 32)
#define MAXE 4          // fixed predicated writes per segment (len>4 ~ never)

typedef float f4 __attribute__((ext_vector_type(4)));

__device__ __forceinline__ void nt_store4(float* p, f4 v) {
    __builtin_nontemporal_store(v, (f4*)p);
}

// LDS pad: +1 float per 32 breaks power-of-2 stride conflicts.
__device__ __forceinline__ int padi(int j) { return j + (j >> 5); }

// ---- 6x6 not-a-knot solve; A compile-time constant -> multipliers fold ----
__device__ __forceinline__ void spline_solve(const float* __restrict__ yy,
                                             int b, int c, float* y, float* Mv)
{
    #pragma unroll
    for (int k = 0; k < NN; ++k)
        y[k] = yy[((size_t)b * NN + k) * CC + c];
    float Aug[NN][NN + 1];
    #pragma unroll
    for (int i = 0; i < NN; ++i)
        #pragma unroll
        for (int j = 0; j < NN + 1; ++j)
            Aug[i][j] = 0.0f;
    Aug[0][0] = 1.0f;  Aug[0][1] = -2.0f;  Aug[0][2] = 1.0f;
    Aug[5][3] = 1.0f;  Aug[5][4] = -2.0f;  Aug[5][5] = 1.0f;
    #pragma unroll
    for (int i = 1; i < NN - 1; ++i) {
        Aug[i][i - 1] = HH / 6.0f;
        Aug[i][i]     = 2.0f * HH / 3.0f;
        Aug[i][i + 1] = HH / 6.0f;
        Aug[i][NN]    = (y[i + 1] - 2.0f * y[i] + y[i - 1]) / HH;
    }
    #pragma unroll
    for (int k = 0; k < NN; ++k) {
        float inv = 1.0f / Aug[k][k];
        #pragma unroll
        for (int i = k + 1; i < NN; ++i) {
            float m = Aug[i][k] * inv;
            #pragma unroll
            for (int j = k; j < NN + 1; ++j)
                Aug[i][j] -= m * Aug[k][j];
        }
    }
    #pragma unroll
    for (int i = NN - 1; i >= 0; --i) {
        float s = Aug[i][NN];
        #pragma unroll
        for (int j = i + 1; j < NN; ++j)
            s -= Aug[i][j] * Mv[j];
        Mv[i] = s / Aug[i][i];
    }
}

__device__ __forceinline__ void horner_coefs(const float* y, const float* Mv,
                                             f4* out5)
{
    const float invh  = 1.0f / HH;
    const float inv6h = 1.0f / (6.0f * HH);
    #pragma unroll
    for (int s = 0; s < NSPAN; ++s) {
        f4 cf;
        cf.x = y[s];
        cf.y = (y[s + 1] - y[s]) * invh - Mv[s] * (HH / 3.0f) - Mv[s + 1] * (HH / 6.0f);
        cf.z = Mv[s] * 0.5f;
        cf.w = (Mv[s + 1] - Mv[s]) * inv6h;
        out5[s] = cf;
    }
}

// ---- setup: per-(row, span) Horner coeffs (a,b,c,d) into workspace ----
__global__ __launch_bounds__(256) void spline_coef_kernel(
    const float* __restrict__ yy, f4* __restrict__ tab)
{
    const int row = blockIdx.x * 256 + threadIdx.x;   // 8192 rows, coalesced in c
    const int b = row / CC;
    const int c = row % CC;
    float y[NN], Mv[NN];
    spline_solve(yy, b, c, y, Mv);
    f4 cf[NSPAN];
    horner_coefs(y, Mv, cf);
    #pragma unroll
    for (int s = 0; s < NSPAN; ++s)
        tab[row * NSPAN + s] = cf[s];
}

// ============================ main kernel ==================================
// R9 structure + DISPATCH-PHASE MIXING: blockIdx -> row permuted so that
// consecutive dispatched blocks have different b (different mask value).
// Copy-blocks (pure streaming) and warp-blocks (compute/LDS) then co-reside
// on every CU at all times, overlapping memory and compute pipes.
template <int TABLE>
__global__ __launch_bounds__(NTHR) void timewarp_kernel(
    const float* __restrict__ x,
    const float* __restrict__ yy,
    const float* __restrict__ mask_rand,
    const f4* __restrict__ tab,
    float* __restrict__ out)
{
    // permuted mapping: b cycles fastest -> adjacent blocks mix warp/copy
    const int b   = blockIdx.x & (BB - 1);       // blk % 64
    const int c   = blockIdx.x >> 6;             // blk / 64, 0..127
    const int row = b * CC + c;
    const int tid = threadIdx.x;

    const float* xrow = x + (size_t)row * TT;
    float* orow       = out + (size_t)row * TT;

    // mask_rand >= 0.5 -> bit-exact copy (uniform per block)
    if (!(mask_rand[b] < 0.5f)) {
        const f4* xi = (const f4*)xrow;
        nt_store4(orow + 4 * tid,          xi[tid]);
        nt_store4(orow + 4 * (tid + NTHR), xi[tid + NTHR]);
        return;
    }

    __shared__ float sh_res[PADSZ];      // padded scatter target
    __shared__ float sh_wsum[NWAVE];     // per-wave scan totals

    // ---- span geometry ----
    const int t0 = tid * EPT;
    int idxA = t0 / 819;  if (idxA > 4) idxA = 4;
    int idxB = idxA + 1;  if (idxB > 4) idxB = 4;
    const float xlA = (float)idxA * HH;
    const float xlB = (float)idxB * HH;
    const float tb  = (float)((idxA + 1) * 819);   // first t belonging to span B

    // ---- all global loads issued up front ----
    const f4 v0 = *(const f4*)(xrow + t0);
    const f4 v1 = *(const f4*)(xrow + t0 + 4);
    // neighbor's first fp value, bit-identical bits from global (L1-hot)
    const float fpb = xrow[(t0 + EPT < TT) ? (t0 + EPT) : (TT - 1)];

    f4 cfA, cfB;
    if (TABLE) {
        cfA = tab[row * NSPAN + idxA];   // lanes share spans -> few lines/wave
        cfB = tab[row * NSPAN + idxB];
    } else {
        float y[NN], Mv[NN];
        f4 cf[NSPAN];
        spline_solve(yy, b, c, y, Mv);
        horner_coefs(y, Mv, cf);
        cfA = cf[0];  cfB = cf[0];
        #pragma unroll
        for (int s = 1; s < NSPAN; ++s) {      // static indices -> cndmask
            if (idxA >= s) cfA = cf[s];
            if (idxB >= s) cfB = cf[s];
        }
    }

    float fpv[EPT];
    fpv[0] = v0.x; fpv[1] = v0.y; fpv[2] = v0.z; fpv[3] = v0.w;
    fpv[4] = v1.x; fpv[5] = v1.y; fpv[6] = v1.z; fpv[7] = v1.w;

    // ---- curve + thread-local inclusive scan (in-place in xp[]) ----
    float xp[EPT + 1];
    float running = 0.0f;
    #pragma unroll
    for (int k = 0; k < EPT; ++k) {
        float ft = (float)(t0 + k);
        bool inB = ft >= tb;
        f4    cf = inB ? cfB : cfA;
        float xl = inB ? xlB : xlA;
        float s  = ft - xl;
        running += fmaf(s, fmaf(s, fmaf(s, cf.w, cf.z), cf.y), cf.x);
        xp[k] = running;
    }
    // curve at t0+EPT (for the lane-63 boundary reconstruction)
    float cN;
    {
        float ft = (float)(t0 + EPT);
        bool inB = ft >= tb;
        f4    cf = inB ? cfB : cfA;
        float xl = inB ? xlB : xlA;
        float s  = ft - xl;
        cN = fmaf(s, fmaf(s, fmaf(s, cf.w, cf.z), cf.y), cf.x);
    }

    // ---- wave scan (shfl) + cross-wave fixup (barrier 1) ----
    const int lane = tid & 63, wid = tid >> 6;
    float ws = running;
    #pragma unroll
    for (int d = 1; d < 64; d <<= 1) {
        float v = __shfl_up(ws, d, 64);
        if (lane >= d) ws += v;
    }
    if (lane == 63) sh_wsum[wid] = ws;
    __syncthreads();                            // B1
    float wo = 0.0f, total = 0.0f;
    #pragma unroll
    for (int w = 0; w < NWAVE; ++w) {           // ascending: order matters for
        float s = sh_wsum[w];                   // the lane-63 bit-exact proof
        total += s;
        if (w < wid) wo += s;
    }
    const float offs  = wo + (ws - running);    // exclusive prefix
    const float scale = 4095.0f / total;

    #pragma unroll
    for (int k = 0; k < EPT; ++k)
        xp[k] = (xp[k] + offs) * scale;

    // Boundary xp[EPT] without a barrier (validated rounds 5-9):
    //  lanes 0..62: shfl_down of neighbor's xp[0] -> exact bits.
    //  lane 63: ((wo + ws) + cN) * scale == neighbor's (cN + wo')*scale
    //  bit-exactly (ascending fixup sum + IEEE commutativity).
    {
        float n = __shfl_down(xp[0], 1, 64);
        float l = ((wo + ws) + cN) * scale;
        xp[EPT] = (lane == 63) ? l : n;         // tid NTHR-1: unused
    }

    // ---- scatter: fixed 8x4 predicated write grid (straight-line) ----
    // segment j owns q in [ceil(xp[j]), ceil(xp[j+1])); len <= 4 essentially
    // always; cold loop handles the remainder.
    #pragma unroll
    for (int k = 0; k < EPT; ++k) {
        const int seg = t0 + k;
        if (seg < TT - 1) {
            float xa = xp[k], xb = xp[k + 1];
            float fa = fpv[k];
            float fb = (k < EPT - 1) ? fpv[k + 1] : fpb;
            float d  = xb - xa;
            float slope = (d > 0.0f) ? (fb - fa) * __builtin_amdgcn_rcpf(d) : 0.0f;
            float a0 = fmaf(-xa, slope, fa);
            int qlo = (int)ceilf(xa);  if (qlo < 0) qlo = 0;
            int qhi = (int)ceilf(xb);  if (qhi > TT) qhi = TT;
            int len = qhi - qlo;
            #pragma unroll
            for (int e = 0; e < MAXE; ++e) {
                if (e < len)
                    sh_res[padi(qlo + e)] = fmaf((float)(qlo + e), slope, a0);
            }
            if (len > MAXE) {                   // cold: essentially never
                for (int q = qlo + MAXE; q < qhi; ++q)
                    sh_res[padi(q)] = fmaf((float)q, slope, a0);
            }
        }
    }
    if (tid == 0) {                             // head: q < xp[0] -> fp[0]
        int q1 = (int)ceilf(xp[0]);  if (q1 > TT) q1 = TT;
        for (int q = 0; q < q1; ++q) sh_res[padi(q)] = fpv[0];
    }
    if (tid == NTHR - 1) {                      // tail: q >= xp[4095] -> fp[4095]
        int q0 = (int)ceilf(xp[EPT - 1]);  if (q0 < 0) q0 = 0;
        for (int q = q0; q < TT; ++q) sh_res[padi(q)] = fpv[EPT - 1];
    }
    __syncthreads();                            // B2: sh_res complete

    // ---- restage: coalesced nontemporal float4 stores ----
    #pragma unroll
    for (int kk = 0; kk < 2; ++kk) {
        int i4  = tid + NTHR * kk;
        int fb4 = 4 * i4;
        int p   = padi(fb4);
        f4 v;
        v.x = sh_res[p + 0];
        v.y = sh_res[p + 1];
        v.z = sh_res[p + 2];
        v.w = sh_res[p + 3];
        nt_store4(orow + fb4, v);
    }
}

extern "C" void kernel_launch(void* const* d_in, const int* in_sizes, int n_in,
                              void* d_out, int out_size, void* d_ws, size_t ws_size,
                              hipStream_t stream) {
    const float* x    = (const float*)d_in[0];   // (64,128,4096) fp32
    const float* yy   = (const float*)d_in[1];   // (64,6,128)    fp32
    const float* mask = (const float*)d_in[2];   // (64,1,1)      fp32
    float* out = (float*)d_out;                  // (64,128,4096) fp32

    if (d_ws != nullptr && ws_size >= TABBYTES) {
        f4* tab = (f4*)d_ws;
        spline_coef_kernel<<<dim3(NROW / 256), dim3(256), 0, stream>>>(yy, tab);
        timewarp_kernel<1><<<dim3(NROW), dim3(NTHR), 0, stream>>>(x, yy, mask, tab, out);
    } else {
        timewarp_kernel<0><<<dim3(NROW), dim3(NTHR), 0, stream>>>(x, yy, mask, nullptr, out);
    }
}